// Round 5
// baseline (2097.614 us; speedup 1.0000x reference)
//
#include <hip/hip_runtime.h>
#include <math.h>

#define NN 4096
#define DIM 784
#define K62 62
#define NSEL 70

// ---------------- init ----------------
__global__ __launch_bounds__(64) void k_init(double* Ssum, double* Lsum) {
    if (threadIdx.x == 0) { Ssum[0] = 0.0; Lsum[0] = 0.0; }
}

// ---------------- squared row norms of x (f64) ----------------
__global__ __launch_bounds__(256) void k_sqnorm(const float* __restrict__ x, double* __restrict__ sqnd) {
    int r = blockIdx.x * 4 + (threadIdx.x >> 6);
    int lane = threadIdx.x & 63;
    const float* xr = x + (size_t)r * DIM;
    double s = 0.0;
    for (int k = lane; k < DIM; k += 64) { double v = (double)xr[k]; s += v * v; }
    for (int o = 32; o > 0; o >>= 1) s += __shfl_down(s, o);
    if (lane == 0) sqnd[r] = s;
}

// ---------------- fused encoder, all arithmetic in f64 ----------------
// conv1(3x3x1x32)+relu+pool -> conv2(3x3x32x32)+relu+pool -> conv3(3x3x32x16)+relu -> dense(784x16)
// LDS <= 64KB via ci-split of conv2 (two halves of 16 input channels).
__global__ __launch_bounds__(256) void k_encoder(const float* __restrict__ x,
    const float* __restrict__ cw1, const float* __restrict__ cb1,
    const float* __restrict__ cw2, const float* __restrict__ cb2,
    const float* __restrict__ cw3, const float* __restrict__ cb3,
    const float* __restrict__ dw, const float* __restrict__ db,
    double* __restrict__ Enc, double* __restrict__ esqd)
{
    __shared__ double h1h[196 * 17];   // 26656 B: conv1 half-channels [pixel][ci16], padded (c3/red overlay later)
    __shared__ double h2s[49 * 33];    // 12936 B: conv2 out [pixel][co], padded
    __shared__ float  wbuf[4608];      // 18432 B: cw2-half / cw3
    __shared__ float  simg[784];       // 3136 B
    __shared__ float  scw1[288];       // 1152 B
    __shared__ float  sb1[32], sb2[32], sb3[16], sdb[16];
    __shared__ double se[16];
    int n = blockIdx.x, t = threadIdx.x;

    if (t < 196) ((float4*)simg)[t] = ((const float4*)(x + (size_t)n * DIM))[t];
    if (t < 72)  ((float4*)scw1)[t] = ((const float4*)cw1)[t];
    if (t < 32) { sb1[t] = cb1[t]; sb2[t] = cb2[t]; }
    if (t < 16) { sb3[t] = cb3[t]; sdb[t] = db[t]; }
    __syncthreads();

    // conv2 accumulators persist across the two ci-halves (t<196 active: 49 px x 4 co-groups of 8)
    int p2 = t >> 2, co8 = (t & 3) * 8;
    int py2 = p2 / 7, px2 = p2 % 7;
    double acc[2][2][8];
    if (t < 196) {
        #pragma unroll
        for (int dy = 0; dy < 2; ++dy)
        #pragma unroll
        for (int dx = 0; dx < 2; ++dx)
        #pragma unroll
        for (int q = 0; q < 8; ++q) acc[dy][dx][q] = (double)sb2[co8 + q];
    }

    for (int h = 0; h < 2; ++h) {
        // ---- conv1 + relu + pool for output channels [16h, 16h+16) ----
        for (int o = t; o < 3136; o += 256) {
            int p = o >> 4, c16 = o & 15, co = h * 16 + c16;
            int py = p / 14, px = p % 14;
            double m = 0.0;
            #pragma unroll
            for (int dy = 0; dy < 2; ++dy)
            #pragma unroll
            for (int dx = 0; dx < 2; ++dx) {
                int y = 2 * py + dy, xx2 = 2 * px + dx;
                double a = (double)sb1[co];
                #pragma unroll
                for (int ky = 0; ky < 3; ++ky) {
                    int iy = y + ky - 1; if ((unsigned)iy >= 28u) continue;
                    #pragma unroll
                    for (int kx = 0; kx < 3; ++kx) {
                        int ix = xx2 + kx - 1; if ((unsigned)ix >= 28u) continue;
                        a = fma((double)simg[iy * 28 + ix], (double)scw1[(ky * 3 + kx) * 32 + co], a);
                    }
                }
                if (a < 0.0) a = 0.0;
                if (a > m) m = a;
            }
            h1h[p * 17 + c16] = m;
        }
        __syncthreads();
        // ---- load cw2 half: for each tap, 512 contiguous floats at tap*1024 + h*512 ----
        for (int idx = t; idx < 1152; idx += 256) {
            int tap = idx >> 7, off = idx & 127;
            ((float4*)wbuf)[tap * 128 + off] = ((const float4*)cw2)[tap * 256 + h * 128 + off];
        }
        __syncthreads();
        // ---- conv2 partial accumulate over this ci-half ----
        if (t < 196) {
            for (int ky = 0; ky < 3; ++ky)
            for (int kx = 0; kx < 3; ++kx) {
                const float* wb0 = &wbuf[(ky * 3 + kx) * 512 + co8];
                for (int ci = 0; ci < 16; ++ci) {
                    float4 wa = *(const float4*)(wb0 + ci * 32);
                    float4 wv = *(const float4*)(wb0 + ci * 32 + 4);
                    double w0 = wa.x, w1 = wa.y, w2 = wa.z, w3 = wa.w;
                    double w4 = wv.x, w5 = wv.y, w6 = wv.z, w7 = wv.w;
                    #pragma unroll
                    for (int dy = 0; dy < 2; ++dy) {
                        int iy = 2 * py2 + dy + ky - 1;
                        if ((unsigned)iy >= 14u) continue;
                        #pragma unroll
                        for (int dx = 0; dx < 2; ++dx) {
                            int ix = 2 * px2 + dx + kx - 1;
                            if ((unsigned)ix >= 14u) continue;
                            double av = h1h[(iy * 14 + ix) * 17 + ci];
                            acc[dy][dx][0] = fma(av, w0, acc[dy][dx][0]);
                            acc[dy][dx][1] = fma(av, w1, acc[dy][dx][1]);
                            acc[dy][dx][2] = fma(av, w2, acc[dy][dx][2]);
                            acc[dy][dx][3] = fma(av, w3, acc[dy][dx][3]);
                            acc[dy][dx][4] = fma(av, w4, acc[dy][dx][4]);
                            acc[dy][dx][5] = fma(av, w5, acc[dy][dx][5]);
                            acc[dy][dx][6] = fma(av, w6, acc[dy][dx][6]);
                            acc[dy][dx][7] = fma(av, w7, acc[dy][dx][7]);
                        }
                    }
                }
            }
        }
        __syncthreads();   // protect h1h/wbuf before next half overwrites
    }
    // ---- conv2 relu + pool -> h2s ----
    if (t < 196) {
        #pragma unroll
        for (int q = 0; q < 8; ++q) {
            double m = 0.0;
            #pragma unroll
            for (int dy = 0; dy < 2; ++dy)
            #pragma unroll
            for (int dx = 0; dx < 2; ++dx) {
                double a = acc[dy][dx][q];
                if (a < 0.0) a = 0.0;
                if (a > m) m = a;
            }
            h2s[p2 * 33 + co8 + q] = m;
        }
    }
    __syncthreads();
    // ---- load cw3 (4608 f) ----
    for (int idx = t; idx < 1152; idx += 256) ((float4*)wbuf)[idx] = ((const float4*)cw3)[idx];
    __syncthreads();
    // ---- conv3 + relu -> c3 (overlay in h1h region) ----
    double* c3  = h1h;          // 784 doubles
    double* red = h1h + 784;    // 256 doubles
    if (t < 196) {
        int p = t >> 2, co4 = (t & 3) * 4;
        int py = p / 7, px = p % 7;
        double a0 = (double)sb3[co4], a1 = (double)sb3[co4 + 1];
        double a2 = (double)sb3[co4 + 2], a3 = (double)sb3[co4 + 3];
        for (int ky = 0; ky < 3; ++ky) {
            int iy = py + ky - 1; if ((unsigned)iy >= 7u) continue;
            for (int kx = 0; kx < 3; ++kx) {
                int ix = px + kx - 1; if ((unsigned)ix >= 7u) continue;
                const double* hp = &h2s[(iy * 7 + ix) * 33];
                const float* wp = &wbuf[((ky * 3 + kx) * 32) * 16 + co4];
                for (int ci = 0; ci < 32; ++ci) {
                    double av = hp[ci];
                    float4 wv = *(const float4*)(wp + ci * 16);
                    a0 = fma(av, (double)wv.x, a0); a1 = fma(av, (double)wv.y, a1);
                    a2 = fma(av, (double)wv.z, a2); a3 = fma(av, (double)wv.w, a3);
                }
            }
        }
        c3[p * 16 + co4 + 0] = a0 > 0.0 ? a0 : 0.0;
        c3[p * 16 + co4 + 1] = a1 > 0.0 ? a1 : 0.0;
        c3[p * 16 + co4 + 2] = a2 > 0.0 ? a2 : 0.0;
        c3[p * 16 + co4 + 3] = a3 > 0.0 ? a3 : 0.0;
    }
    __syncthreads();
    // ---- dense 784x16 (dw read from global; identical across blocks -> L2-resident) ----
    {
        int part = t >> 4, o = t & 15, j0 = part * 49;
        double s = 0.0;
        for (int j = 0; j < 49; ++j) s = fma(c3[j0 + j], (double)dw[(size_t)(j0 + j) * 16 + o], s);
        red[part * 16 + o] = s;
    }
    __syncthreads();
    if (t < 16) {
        double e = (double)sdb[t];
        for (int q = 0; q < 16; ++q) e += red[q * 16 + t];
        Enc[(size_t)n * 16 + t] = e;
        se[t] = e;
    }
    __syncthreads();
    if (t == 0) {
        double s = 0.0;
        for (int q = 0; q < 16; ++q) s += se[q] * se[q];
        esqd[n] = s;
    }
}

// ---------------- Gram f64 -> fused d^2, stored as correctly-rounded f32 keys ----------------
__global__ __launch_bounds__(256) void k_gramd(const float* __restrict__ x, const double* __restrict__ sqnd,
                                               float* __restrict__ Dm) {
    __shared__ float As[16][68];
    __shared__ float Bs[16][68];
    int id = blockIdx.x;
    int bi = (int)((sqrtf(8.f * (float)id + 1.f) - 1.f) * 0.5f);
    while ((bi + 1) * (bi + 2) / 2 <= id) ++bi;
    while (bi * (bi + 1) / 2 > id) --bi;
    int bj = id - bi * (bi + 1) / 2;
    int i0 = bi * 64, j0 = bj * 64;
    int t = threadIdx.x;
    int tx = t & 15, ty = t >> 4;
    int lrow = t >> 2, lk4 = (t & 3) * 4;
    double acc[4][4];
    #pragma unroll
    for (int r = 0; r < 4; ++r)
    #pragma unroll
    for (int c = 0; c < 4; ++c) acc[r][c] = 0.0;
    const float* arow = x + (size_t)(i0 + lrow) * DIM + lk4;
    const float* brow = x + (size_t)(j0 + lrow) * DIM + lk4;
    for (int kk = 0; kk < DIM; kk += 16) {
        float4 a = *(const float4*)(arow + kk);
        float4 b = *(const float4*)(brow + kk);
        __syncthreads();
        As[lk4 + 0][lrow] = a.x; As[lk4 + 1][lrow] = a.y; As[lk4 + 2][lrow] = a.z; As[lk4 + 3][lrow] = a.w;
        Bs[lk4 + 0][lrow] = b.x; Bs[lk4 + 1][lrow] = b.y; Bs[lk4 + 2][lrow] = b.z; Bs[lk4 + 3][lrow] = b.w;
        __syncthreads();
        #pragma unroll
        for (int k = 0; k < 16; ++k) {
            float4 af = *(const float4*)&As[k][ty * 4];
            float4 bf = *(const float4*)&Bs[k][tx * 4];
            double ad[4] = {(double)af.x, (double)af.y, (double)af.z, (double)af.w};
            double bd[4] = {(double)bf.x, (double)bf.y, (double)bf.z, (double)bf.w};
            #pragma unroll
            for (int r = 0; r < 4; ++r)
            #pragma unroll
            for (int c = 0; c < 4; ++c) acc[r][c] = fma(ad[r], bd[c], acc[r][c]);
        }
    }
    double si[4], sj[4];
    #pragma unroll
    for (int r = 0; r < 4; ++r) si[r] = sqnd[i0 + ty * 4 + r];
    #pragma unroll
    for (int c = 0; c < 4; ++c) sj[c] = sqnd[j0 + tx * 4 + c];
    #pragma unroll
    for (int r = 0; r < 4; ++r) {
        float f[4];
        #pragma unroll
        for (int c = 0; c < 4; ++c) {
            double d2 = si[r] + sj[c] - 2.0 * acc[r][c];
            f[c] = (float)fmax(d2, 1e-12);
        }
        *(float4*)(Dm + (size_t)(i0 + ty * 4 + r) * NN + j0 + tx * 4) = make_float4(f[0], f[1], f[2], f[3]);
        if (bi != bj) {
            #pragma unroll
            for (int c = 0; c < 4; ++c)
                Dm[(size_t)(j0 + tx * 4 + c) * NN + (i0 + ty * 4 + r)] = f[c];
        }
    }
}

// ---------------- selection: iterative argmax top-70 (f32 keys), f64 refine, rank on sqrt ----------------
__global__ __launch_bounds__(256) void k_topsel(const float* __restrict__ Dm, const double* __restrict__ sqnd,
                                                const float* __restrict__ x,
                                                double* __restrict__ topvd, int* __restrict__ topi) {
    __shared__ unsigned long long skey[4096];
    __shared__ float xi[DIM];
    __shared__ unsigned long long wmax[4];
    __shared__ unsigned long long sbest;
    __shared__ int cj[NSEL];
    __shared__ double cvd[NSEL];
    int i = blockIdx.x, t = threadIdx.x;
    const float* drow = Dm + (size_t)i * NN;
    for (int s = 0; s < 16; ++s) {
        int j = t + s * 256;
        unsigned u = __float_as_uint(drow[j]);   // positive float: bit order == numeric order
        if (j == i) u = 0u;                      // exclude self
        skey[j] = ((unsigned long long)u << 32) | (unsigned)(NN - 1 - j);  // ties -> smaller j first
    }
    for (int d = t; d < DIM; d += 256) xi[d] = x[(size_t)i * DIM + d];
    __syncthreads();
    int lane = t & 63, wv = t >> 6;
    for (int it = 0; it < NSEL; ++it) {
        unsigned long long best = 0; int bs = -1;
        #pragma unroll
        for (int s = 0; s < 16; ++s) {
            unsigned long long v = skey[t + s * 256];
            if (v > best) { best = v; bs = s; }
        }
        unsigned long long bw = best;
        for (int o = 32; o > 0; o >>= 1) {
            unsigned long long ov = __shfl_down(bw, o);
            if (ov > bw) bw = ov;
        }
        if (lane == 0) wmax[wv] = bw;
        __syncthreads();
        if (t == 0) {
            unsigned long long m = wmax[0];
            for (int q = 1; q < 4; ++q) if (wmax[q] > m) m = wmax[q];
            sbest = m;
            cj[it] = (NN - 1) - (int)(m & 0xFFFFFFFFu);
        }
        __syncthreads();
        if (bs >= 0 && best == sbest) skey[t + bs * 256] = 0;   // unique owner clears
        __syncthreads();
    }
    // exact f64 distance for the 70 candidates
    double sqi_d = sqnd[i];
    for (int c = wv; c < NSEL; c += 4) {
        const float* xj = x + (size_t)cj[c] * DIM;
        double s = 0.0;
        for (int d = lane; d < DIM; d += 64) s = fma((double)xi[d], (double)xj[d], s);
        for (int o = 32; o > 0; o >>= 1) s += __shfl_down(s, o);
        if (lane == 0) cvd[c] = sqrt(fmax(sqi_d + sqnd[cj[c]] - 2.0 * s, 1e-12));
    }
    __syncthreads();
    // rank on (distance desc, index asc) — matches top_k on sqrt'd values; drop rank 0
    if (t < NSEL) {
        double v = cvd[t]; int jj = cj[t];
        int r = 0;
        for (int c2 = 0; c2 < NSEL; ++c2) {
            double v2 = cvd[c2];
            if (v2 > v || (v2 == v && cj[c2] < jj)) ++r;
        }
        if (r >= 1 && r < 63) {
            topvd[(size_t)i * K62 + r - 1] = v;
            topi[(size_t)i * K62 + r - 1] = jj;
        }
    }
}

// ---------------- encoded distances (np's cancellation form, f64) + ratio sum ----------------
__global__ __launch_bounds__(256) void k_ratio(const double* __restrict__ Enc, const double* __restrict__ esqd,
                                               const double* __restrict__ topvd, const int* __restrict__ topi,
                                               double* __restrict__ vencd, double* __restrict__ Ssum) {
    int r = blockIdx.x * 4 + (threadIdx.x >> 6);
    int lane = threadIdx.x & 63;
    double ratio = 0.0;
    if (lane < K62) {
        int j = topi[(size_t)r * K62 + lane];
        const double* Er = Enc + (size_t)r * 16;
        const double* Ej = Enc + (size_t)j * 16;
        double dot = 0.0;
        #pragma unroll
        for (int q = 0; q < 16; ++q) dot = fma(Er[q], Ej[q], dot);
        double ve = sqrt(fmax(esqd[r] + esqd[j] - 2.0 * dot, 1e-12));
        vencd[(size_t)r * K62 + lane] = ve;
        ratio = topvd[(size_t)r * K62 + lane] / ve;
    }
    for (int o = 32; o > 0; o >>= 1) ratio += __shfl_down(ratio, o);
    if (lane == 0) atomicAdd(Ssum, ratio);
}

// ---------------- final loss ----------------
__global__ __launch_bounds__(256) void k_loss(const double* __restrict__ topvd, const double* __restrict__ vencd,
                                              const double* __restrict__ Ssum, double* __restrict__ Lsum) {
    int r = blockIdx.x * 4 + (threadIdx.x >> 6);
    int lane = threadIdx.x & 63;
    double m = Ssum[0] * (1.0 / (4096.0 * 62.0));
    double v = -1.0;
    if (lane < K62) {
        double d = topvd[(size_t)r * K62 + lane] - m * vencd[(size_t)r * K62 + lane];
        v = d * d;
    }
    for (int o = 32; o > 0; o >>= 1) { double ov = __shfl_down(v, o); v = (ov > v) ? ov : v; }
    if (lane == 0) atomicAdd(Lsum, v);
}

__global__ __launch_bounds__(64) void k_final(const double* __restrict__ Lsum, float* __restrict__ out) {
    if (threadIdx.x == 0) out[0] = (float)(Lsum[0] * (1.0 / 4096.0));
}

extern "C" void kernel_launch(void* const* d_in, const int* in_sizes, int n_in,
                              void* d_out, int out_size, void* d_ws, size_t ws_size,
                              hipStream_t stream) {
    const float* x   = (const float*)d_in[0];
    const float* cw1 = (const float*)d_in[1];
    const float* cb1 = (const float*)d_in[2];
    const float* cw2 = (const float*)d_in[3];
    const float* cb2 = (const float*)d_in[4];
    const float* cw3 = (const float*)d_in[5];
    const float* cb3 = (const float*)d_in[6];
    const float* dw  = (const float*)d_in[7];
    const float* db  = (const float*)d_in[8];

    float*  ws    = (float*)d_ws;
    float*  Dm    = ws;                          // 16,777,216 f = 64 MB
    double* Enc   = (double*)(ws + 16777216);    // 65,536 d (byte off 67,108,864; %8==0)
    double* esqd  = Enc + 65536;                 // 4,096 d
    double* sqnd  = esqd + 4096;                 // 4,096 d
    double* topvd = sqnd + 4096;                 // 253,952 d
    double* vencd = topvd + 253952;              // 253,952 d
    double* Ssum  = vencd + 253952;              // 1 d
    double* Lsum  = Ssum + 1;                    // 1 d
    int*    topi  = (int*)(Lsum + 1);            // 253,952 i
    float*  out   = (float*)d_out;

    k_init<<<1, 64, 0, stream>>>(Ssum, Lsum);
    k_sqnorm<<<1024, 256, 0, stream>>>(x, sqnd);
    k_encoder<<<4096, 256, 0, stream>>>(x, cw1, cb1, cw2, cb2, cw3, cb3, dw, db, Enc, esqd);
    k_gramd<<<2080, 256, 0, stream>>>(x, sqnd, Dm);
    k_topsel<<<4096, 256, 0, stream>>>(Dm, sqnd, x, topvd, topi);
    k_ratio<<<1024, 256, 0, stream>>>(Enc, esqd, topvd, topi, vencd, Ssum);
    k_loss<<<1024, 256, 0, stream>>>(topvd, vencd, Ssum, Lsum);
    k_final<<<1, 64, 0, stream>>>(Lsum, out);
}